// Round 1
// baseline (442.161 us; speedup 1.0000x reference)
//
#include <hip/hip_runtime.h>

#define NN 200000
#define NEGV -1000000000.0f

typedef __attribute__((ext_vector_type(8))) short bf16x8;
typedef __attribute__((ext_vector_type(4))) float f32x4;

__device__ __forceinline__ float bf2f(unsigned short u){
  unsigned int x = ((unsigned int)u) << 16;
  return __builtin_bit_cast(float, x);
}
__device__ __forceinline__ unsigned short f2bf(float f){
  unsigned int x = __builtin_bit_cast(unsigned int, f);
  x += 0x7fffu + ((x >> 16) & 1u);
  return (unsigned short)(x >> 16);
}

// ---------------- workspace layout (bytes) ----------------
static constexpr size_t OFF_RK     = 0;                       // N floats (+pad)
static constexpr size_t OFF_RV     = OFF_RK + 800256;
static constexpr size_t OFF_LOGITS = OFF_RV + 800256;         // 8*N floats
static constexpr size_t OFF_SCORES = OFF_LOGITS + 6400000;    // N floats
static constexpr size_t OFF_QUERY  = OFF_SCORES + 800256;     // 256 f
static constexpr size_t OFF_Q2     = OFF_QUERY + 1024;        // 256 f
static constexpr size_t OFF_AH     = OFF_Q2 + 1024;           // 8*256 f
static constexpr size_t OFF_A2     = OFF_AH + 8192;           // 8*256 f
static constexpr size_t OFF_CONSTS = OFF_A2 + 8192;           // cb[8], cK[8]
static constexpr size_t OFF_BIMG   = OFF_CONSTS + 256;        // 8*528*64 B
static constexpr size_t OFF_LSTAT  = OFF_BIMG + 270336;       // 64*(m,z)
static constexpr size_t OFF_MZ     = OFF_LSTAT + 512;         // M[8], Z[8]
static constexpr size_t OFF_KATTN  = OFF_MZ + 64;             // 256 f
static constexpr size_t OFF_KB     = OFF_KATTN + 1024;        // 1 f (+pad)
static constexpr size_t OFF_UPART  = OFF_KB + 256;            // 512*8*256 f
static constexpr size_t OFF_TPART  = OFF_UPART + (size_t)512*2048*4; // 512*8 f
static constexpr size_t OFF_U      = OFF_TPART + 16384;       // 8*256 f
static constexpr size_t OFF_T      = OFF_U + 8192;            // 8 f (+pad)
static constexpr size_t OFF_P3STAT = OFF_T + 64;              // 512*(m,z)
static constexpr size_t OFF_MZ3    = OFF_P3STAT + 4096;       // 2 f

// ---------------- tiny prep chain ----------------
__global__ void k_query(const float* __restrict__ ctx, const float* __restrict__ Wc,
                        const float* __restrict__ bc, float* __restrict__ query){
  int e = blockIdx.x, t = threadIdx.x;
  float p = 0.f;
  #pragma unroll
  for (int r = 0; r < 3; r++){ int j = r*256 + t; p += ctx[j] * Wc[e*768 + j]; }
  #pragma unroll
  for (int m = 32; m; m >>= 1) p += __shfl_xor(p, m);
  __shared__ float red[4];
  if ((t & 63) == 0) red[t >> 6] = p;
  __syncthreads();
  if (t == 0) query[e] = red[0] + red[1] + red[2] + red[3] + bc[e];
}

__global__ void k_q2(const float* __restrict__ query, const float* __restrict__ ipw,
                     const float* __restrict__ ipb, float* __restrict__ q2){
  int d = blockIdx.x, t = threadIdx.x;
  float p = query[t] * ipw[d*256 + t];
  #pragma unroll
  for (int m = 32; m; m >>= 1) p += __shfl_xor(p, m);
  __shared__ float red[4];
  if ((t & 63) == 0) red[t >> 6] = p;
  __syncthreads();
  if (t == 0) q2[d] = red[0] + red[1] + red[2] + red[3] + ipb[d];
}

__global__ void k_A(const float* __restrict__ q2, const float* __restrict__ ipw,
                    const float* __restrict__ ipb, float* __restrict__ AH, float* __restrict__ consts){
  int h = blockIdx.x, t = threadIdx.x;
  __shared__ float qs[32];
  if (t < 32) qs[t] = q2[h*32 + t];
  __syncthreads();
  float a = 0.f;
  #pragma unroll
  for (int d = 0; d < 32; d++) a += qs[d] * ipw[(256 + h*32 + d)*256 + t];
  AH[h*256 + t] = a;
  if (t == 0){
    float ck = 0.f;
    for (int d = 0; d < 32; d++) ck += qs[d] * ipb[256 + h*32 + d];
    consts[8 + h] = ck;
  }
}

__global__ void k_A2(const float* __restrict__ AH, const float* __restrict__ Wk,
                     const float* __restrict__ bk, float* __restrict__ A2, float* __restrict__ consts){
  int h = blockIdx.x, t = threadIdx.x;
  __shared__ float as[256];
  as[t] = AH[h*256 + t];
  __syncthreads();
  float a = 0.f;
  for (int e = 0; e < 256; e++) a += as[e] * Wk[e*256 + t];
  A2[h*256 + t] = a;
  float c = as[t] * bk[t];
  #pragma unroll
  for (int m = 32; m; m >>= 1) c += __shfl_xor(c, m);
  __shared__ float red[4];
  if ((t & 63) == 0) red[t >> 6] = c;
  __syncthreads();
  if (t == 0) consts[h] = red[0] + red[1] + red[2] + red[3];
}

// Pre-swizzled bf16 B image: per k-step s (8), col (528: Wk|Wv|A2+pad), kg (4):
// 16B granule at s*33792 + ((col*64 + kg*16) ^ ((col&7)<<4))
__global__ void k_bimg(const float* __restrict__ Wk, const float* __restrict__ Wv,
                       const float* __restrict__ A2, unsigned char* __restrict__ bimg){
  int g = blockIdx.x*256 + threadIdx.x;
  if (g >= 8*528*4) return;
  int s = g / (528*4);
  int rem = g % (528*4);
  int col = rem >> 2, kg = rem & 3;
  int j0 = s*32 + kg*8;
  const float* src = nullptr;
  if (col < 256) src = Wk + col*256 + j0;
  else if (col < 512) src = Wv + (col-256)*256 + j0;
  else if (col < 520) src = A2 + (col-512)*256 + j0;
  unsigned short u[8];
  #pragma unroll
  for (int i = 0; i < 8; i++) u[i] = src ? f2bf(src[i]) : (unsigned short)0;
  uint4 o;
  o.x = (unsigned int)u[0] | ((unsigned int)u[1] << 16);
  o.y = (unsigned int)u[2] | ((unsigned int)u[3] << 16);
  o.z = (unsigned int)u[4] | ((unsigned int)u[5] << 16);
  o.w = (unsigned int)u[6] | ((unsigned int)u[7] << 16);
  unsigned int addr = (unsigned int)((col*64 + kg*16) ^ ((col & 7) << 4));
  *(uint4*)(bimg + (size_t)s*33792 + addr) = o;
}

// ---------------- main fused GEMM: emb @ [Wk^T | Wv^T | A2^T] ----------------
// block = 256 thr (4 waves), 64 nodes/block; wave w owns node strip w*16..w*16+15.
// MFMA 16x16x32 bf16; A: row=lane&15, k=(lane>>4)*8+i; B: col=lane&15, same k;
// D: col=lane&15, row=(lane>>4)*4+reg.
__launch_bounds__(256, 2)
__global__ void k_main(const float* __restrict__ emb, const unsigned char* __restrict__ bimg,
                       const int* __restrict__ mask, const float* __restrict__ consts,
                       float* __restrict__ rk_g, float* __restrict__ rv_g, float* __restrict__ logits){
  __shared__ __align__(16) unsigned char smA[32768];   // 64 nodes x 256 bf16, XOR-swizzled
  __shared__ __align__(16) unsigned char smB[33792];   // 528 cols x 32 k bf16, XOR-swizzled
  const int tid = threadIdx.x;
  const int lane = tid & 63, wave = tid >> 6;
  const int nb0 = blockIdx.x * 64;
  const int colbase = lane & 15, kg = lane >> 4;

  // Stage A: 2048 16B-granules (node, jb) — fp32 -> bf16, swizzled ds_write
  #pragma unroll
  for (int it = 0; it < 8; it++){
    int g = it*256 + tid;
    int node = g >> 5, jb = g & 31;
    const float* srcp = emb + (size_t)(nb0 + node)*256 + jb*8;
    float4 f0 = *(const float4*)srcp;
    float4 f1 = *(const float4*)(srcp + 4);
    uint4 o;
    o.x = (unsigned int)f2bf(f0.x) | ((unsigned int)f2bf(f0.y) << 16);
    o.y = (unsigned int)f2bf(f0.z) | ((unsigned int)f2bf(f0.w) << 16);
    o.z = (unsigned int)f2bf(f1.x) | ((unsigned int)f2bf(f1.y) << 16);
    o.w = (unsigned int)f2bf(f1.z) | ((unsigned int)f2bf(f1.w) << 16);
    unsigned int a = (unsigned int)((node*512 + jb*16) ^ ((node & 7) << 4));
    *(uint4*)(smA + a) = o;
  }

  f32x4 acc[33];
  #pragma unroll
  for (int c = 0; c < 33; c++) acc[c] = (f32x4){0.f, 0.f, 0.f, 0.f};

  for (int s = 0; s < 8; s++){
    __syncthreads();               // previous compute done / A staged
    #pragma unroll
    for (int it = 0; it < 9; it++){
      int g = it*256 + tid;
      if (g < 2112){
        uint4 d = *(const uint4*)(bimg + (size_t)s*33792 + (size_t)g*16);
        *(uint4*)(smB + g*16) = d;
      }
    }
    __syncthreads();
    int nodeA = wave*16 + colbase;
    unsigned int aaddr = (unsigned int)((nodeA*512 + (s*4 + kg)*16) ^ ((nodeA & 7) << 4));
    bf16x8 af = *(const bf16x8*)(smA + aaddr);
    #pragma unroll
    for (int c = 0; c < 33; c++){
      unsigned int baddr = (unsigned int)((((c*16 + colbase)*64 + kg*16)) ^ ((colbase & 7) << 4));
      bf16x8 bf = *(const bf16x8*)(smB + baddr);
      acc[c] = __builtin_amdgcn_mfma_f32_16x16x32_bf16(af, bf, acc[c], 0, 0, 0);
    }
  }

  // Epilogue: norms + masked logits
  const float rs32 = 0.17677669529663688f; // 1/sqrt(32)
  float cbv = 0.f, ckv = 0.f;
  if (colbase < 8){ cbv = consts[colbase]; ckv = consts[8 + colbase]; }
  #pragma unroll
  for (int i = 0; i < 4; i++){
    float pk = 0.f, pv = 0.f;
    #pragma unroll
    for (int c = 0; c < 16; c++) pk += acc[c][i]*acc[c][i];
    #pragma unroll
    for (int c = 16; c < 32; c++) pv += acc[c][i]*acc[c][i];
    #pragma unroll
    for (int m = 1; m < 16; m <<= 1){ pk += __shfl_xor(pk, m); pv += __shfl_xor(pv, m); }
    float rk = fmaxf(sqrtf(pk), 1e-12f);
    float rv = fmaxf(sqrtf(pv), 1e-12f);
    int n = nb0 + wave*16 + kg*4 + i;
    if (colbase == 0){ rk_g[n] = rk; rv_g[n] = rv; }
    if (colbase < 8){
      bool valid = (mask[n] == 0);
      float lg = valid ? ((acc[32][i] + cbv) * rs32 / rk + ckv * rs32) : NEGV;
      logits[(size_t)colbase*NN + n] = lg;
    }
  }
}

// ---------------- attention softmax stats over logits ----------------
__global__ void k_lstats(const float* __restrict__ logits, float* __restrict__ lstat){
  int b = blockIdx.x;            // 64 = 8 heads x 8 slices
  int h = b >> 3, sl = b & 7;
  int t = threadIdx.x;
  const float* L = logits + (size_t)h*NN + (size_t)sl*25000;
  float m = -3.0e38f, z = 0.f;
  for (int i = t; i < 25000; i += 256){
    float l = L[i];
    float M = fmaxf(m, l);
    z = z*expf(m - M) + expf(l - M);
    m = M;
  }
  #pragma unroll
  for (int mm = 1; mm < 64; mm <<= 1){
    float m2 = __shfl_xor(m, mm), z2 = __shfl_xor(z, mm);
    float M = fmaxf(m, m2);
    z = z*expf(m - M) + z2*expf(m2 - M);
    m = M;
  }
  __shared__ float rm[4], rz[4];
  if ((t & 63) == 0){ rm[t>>6] = m; rz[t>>6] = z; }
  __syncthreads();
  if (t == 0){
    float M = m, Z = z;
    for (int w = 1; w < 4; w++){
      float M2 = fmaxf(M, rm[w]);
      Z = Z*expf(M - M2) + rz[w]*expf(rm[w] - M2);
      M = M2;
    }
    lstat[b*2] = M; lstat[b*2+1] = Z;
  }
}

__global__ void k_mz(const float* __restrict__ lstat, float* __restrict__ MZ){
  int h = threadIdx.x;
  if (h >= 8) return;
  float M = -3.0e38f, Z = 0.f;
  for (int sl = 0; sl < 8; sl++){
    float m2 = lstat[(h*8+sl)*2], z2 = lstat[(h*8+sl)*2+1];
    float Mn = fmaxf(M, m2);
    Z = Z*expf(M - Mn) + z2*expf(m2 - Mn);
    M = Mn;
  }
  MZ[h] = M; MZ[8+h] = Z;
}

// ---------------- weighted emb reduction: u[h] = sum_n exp(l-M)/rv * emb_n ----------------
__launch_bounds__(256)
__global__ void k_wsum(const float* __restrict__ emb, const float* __restrict__ logits,
                       const float* __restrict__ rv_g, const float* __restrict__ MZ,
                       float* __restrict__ upart, float* __restrict__ tpart){
  int tid = threadIdx.x, lane = tid & 63, wave = tid >> 6;
  int gw = blockIdx.x*4 + wave;           // 0..2047
  float Mh = MZ[lane & 7];
  f32x4 ua[8];
  #pragma unroll
  for (int h = 0; h < 8; h++) ua[h] = (f32x4){0.f,0.f,0.f,0.f};
  float tacc = 0.f;
  for (int n = gw; n < NN; n += 2048){
    float4 ev = *(const float4*)(emb + (size_t)n*256 + lane*4);
    float lg = logits[(size_t)(lane & 7)*NN + n];
    float rvn = rv_g[n];
    float coef = expf(lg - Mh) / rvn;
    tacc += coef;
    #pragma unroll
    for (int h = 0; h < 8; h++){
      float ch = __shfl(coef, h);
      ua[h][0] += ch*ev.x; ua[h][1] += ch*ev.y; ua[h][2] += ch*ev.z; ua[h][3] += ch*ev.w;
    }
  }
  __shared__ float ub[4][8][256];
  __shared__ float tb[4][8];
  #pragma unroll
  for (int h = 0; h < 8; h++){
    ub[wave][h][lane*4+0] = ua[h][0]; ub[wave][h][lane*4+1] = ua[h][1];
    ub[wave][h][lane*4+2] = ua[h][2]; ub[wave][h][lane*4+3] = ua[h][3];
  }
  if (lane < 8) tb[wave][lane] = tacc;
  __syncthreads();
  #pragma unroll
  for (int rep = 0; rep < 8; rep++){
    int idx = rep*256 + tid;
    int h = idx >> 8, j = idx & 255;
    float s = ub[0][h][j] + ub[1][h][j] + ub[2][h][j] + ub[3][h][j];
    upart[(size_t)blockIdx.x*2048 + h*256 + j] = s;
  }
  if (tid < 8) tpart[blockIdx.x*8 + tid] = tb[0][tid]+tb[1][tid]+tb[2][tid]+tb[3][tid];
}

__global__ void k_ured(const float* __restrict__ upart, const float* __restrict__ tpart,
                       float* __restrict__ U, float* __restrict__ T){
  int h = blockIdx.x, j = threadIdx.x;
  float s = 0.f;
  for (int b = 0; b < 512; b++) s += upart[(size_t)b*2048 + h*256 + j];
  U[h*256 + j] = s;
  float tp = 0.f;
  if (j < 64){
    for (int i = 0; i < 8; i++) tp += tpart[(j*8 + i)*8 + h];
  }
  #pragma unroll
  for (int m = 1; m < 64; m <<= 1) tp += __shfl_xor(tp, m);
  if (j == 0) T[h] = tp;
}

// ---------------- tiny attention/projection chain ----------------
__global__ void k_attn(const float* __restrict__ U, const float* __restrict__ T,
                       const float* __restrict__ MZ,
                       const float* __restrict__ Wv, const float* __restrict__ bv,
                       const float* __restrict__ ipw, const float* __restrict__ ipb,
                       const float* __restrict__ opw, const float* __restrict__ opb,
                       const float* __restrict__ Wo, const float* __restrict__ bo,
                       const float* __restrict__ Wk, const float* __restrict__ bk,
                       float* __restrict__ kattn, float* __restrict__ kbout){
  int t = threadIdx.x;
  __shared__ float u[8][256], sh[8][256];
  __shared__ float a1[256], o1[256], af[256];
  __shared__ float red[4];
  #pragma unroll
  for (int h = 0; h < 8; h++) u[h][t] = U[h*256 + t];
  __syncthreads();
  // s[h][e] = (Wv u_h + bv t_h)/Z_h
  {
    float accs[8];
    #pragma unroll
    for (int h = 0; h < 8; h++) accs[h] = 0.f;
    for (int j = 0; j < 256; j++){
      float wv = Wv[t*256 + j];
      #pragma unroll
      for (int h = 0; h < 8; h++) accs[h] += wv * u[h][j];
    }
    #pragma unroll
    for (int h = 0; h < 8; h++) sh[h][t] = (accs[h] + bv[t]*T[h]) / MZ[8+h];
  }
  __syncthreads();
  // attn per head via wv2 rows 512..767, + bv2 (sum w = 1)
  {
    int h = t >> 5;
    float a = 0.f;
    for (int j = 0; j < 256; j++) a += ipw[(512 + t)*256 + j] * sh[h][j];
    a1[t] = a + ipb[512 + t];
  }
  __syncthreads();
  { float a = 0.f; for (int j = 0; j < 256; j++) a += opw[t*256 + j]*a1[j]; o1[t] = a + opb[t]; }
  __syncthreads();
  float o2v;
  { float a = 0.f; for (int j = 0; j < 256; j++) a += Wo[t*256 + j]*o1[j]; o2v = a + bo[t]; }
  {
    float sq = o2v*o2v;
    #pragma unroll
    for (int m = 1; m < 64; m <<= 1) sq += __shfl_xor(sq, m);
    if ((t & 63) == 0) red[t >> 6] = sq;
    __syncthreads();
    float nrm = fmaxf(sqrtf(red[0]+red[1]+red[2]+red[3]), 1e-12f);
    af[t] = o2v / nrm;
  }
  __syncthreads();
  { float a = 0.f; for (int e = 0; e < 256; e++) a += af[e]*Wk[e*256 + t]; kattn[t] = a; }
  {
    float c = af[t]*bk[t];
    #pragma unroll
    for (int m = 1; m < 64; m <<= 1) c += __shfl_xor(c, m);
    __syncthreads();              // all reads of red (norm) done before reuse
    if ((t & 63) == 0) red[t >> 6] = c;
    __syncthreads();
    if (t == 0) kbout[0] = red[0]+red[1]+red[2]+red[3];
  }
}

// ---------------- scores + online softmax stats ----------------
__launch_bounds__(256)
__global__ void k_scores(const float* __restrict__ emb, const float* __restrict__ rk_g,
                         const int* __restrict__ mask, const float* __restrict__ kattn,
                         const float* __restrict__ kbp, float* __restrict__ scores,
                         float* __restrict__ p3stat){
  int tid = threadIdx.x, lane = tid & 63, wave = tid >> 6;
  __shared__ float ka[256];
  ka[tid] = kattn[tid];
  __syncthreads();
  float kb = kbp[0];
  float4 kav = *(const float4*)(ka + lane*4);
  int gw = blockIdx.x*4 + wave;
  float m = -3.0e38f, z = 0.f;
  for (int n = gw; n < NN; n += 2048){
    float4 ev = *(const float4*)(emb + (size_t)n*256 + lane*4);
    float d = ev.x*kav.x + ev.y*kav.y + ev.z*kav.z + ev.w*kav.w;
    #pragma unroll
    for (int mm = 1; mm < 64; mm <<= 1) d += __shfl_xor(d, mm);
    float sc = (mask[n] == 0) ? ((d + kb) / rk_g[n]) : NEGV;
    if (lane == 0){
      scores[n] = sc;
      float M = fmaxf(m, sc);
      z = z*expf(m - M) + expf(sc - M);
      m = M;
    }
  }
  __shared__ float rm[4], rz[4];
  if (lane == 0){ rm[wave] = m; rz[wave] = z; }
  __syncthreads();
  if (tid == 0){
    float M = rm[0], Z = rz[0];
    for (int w = 1; w < 4; w++){
      float M2 = fmaxf(M, rm[w]);
      Z = Z*expf(M - M2) + rz[w]*expf(rm[w] - M2);
      M = M2;
    }
    p3stat[blockIdx.x*2] = M; p3stat[blockIdx.x*2+1] = Z;
  }
}

__global__ void k_mz3(const float* __restrict__ p3stat, float* __restrict__ MZ3){
  int t = threadIdx.x;
  float m = p3stat[t*2], z = p3stat[t*2+1];
  {
    float m2 = p3stat[(t+256)*2], z2 = p3stat[(t+256)*2+1];
    float M = fmaxf(m, m2); z = z*expf(m-M) + z2*expf(m2-M); m = M;
  }
  #pragma unroll
  for (int mm = 1; mm < 64; mm <<= 1){
    float ms = __shfl_xor(m, mm), zs = __shfl_xor(z, mm);
    float Mx = fmaxf(m, ms); z = z*expf(m-Mx) + zs*expf(ms-Mx); m = Mx;
  }
  __shared__ float rm[4], rz[4];
  if ((t&63)==0){ rm[t>>6]=m; rz[t>>6]=z; }
  __syncthreads();
  if (t==0){
    float M=rm[0], Z=rz[0];
    for (int w=1; w<4; w++){ float Mx=fmaxf(M,rm[w]); Z=Z*expf(M-Mx)+rz[w]*expf(rm[w]-Mx); M=Mx; }
    MZ3[0]=M; MZ3[1]=Z;
  }
}

__global__ void k_probs(const float* __restrict__ scores, const float* __restrict__ MZ3,
                        float* __restrict__ out){
  float M = MZ3[0], iZ = 1.0f / MZ3[1];
  for (int n = blockIdx.x*256 + threadIdx.x; n < NN; n += 512*256)
    out[n] = expf(scores[n] - M) * iZ;
}

// ---------------- launcher ----------------
extern "C" void kernel_launch(void* const* d_in, const int* in_sizes, int n_in,
                              void* d_out, int out_size, void* d_ws, size_t ws_size,
                              hipStream_t stream){
  (void)in_sizes; (void)n_in; (void)out_size; (void)ws_size;
  const float* ctx = (const float*)d_in[0];
  const float* emb = (const float*)d_in[1];
  const int*   mask= (const int*)d_in[2];
  const float* Wc  = (const float*)d_in[3];
  const float* bc  = (const float*)d_in[4];
  const float* Wk  = (const float*)d_in[5];
  const float* bk  = (const float*)d_in[6];
  const float* Wv  = (const float*)d_in[7];
  const float* bv  = (const float*)d_in[8];
  const float* ipw = (const float*)d_in[9];
  const float* ipb = (const float*)d_in[10];
  const float* opw = (const float*)d_in[11];
  const float* opb = (const float*)d_in[12];
  const float* Wo  = (const float*)d_in[13];
  const float* bo  = (const float*)d_in[14];
  float* out = (float*)d_out;
  char* ws = (char*)d_ws;

  float* rk     = (float*)(ws + OFF_RK);
  float* rv     = (float*)(ws + OFF_RV);
  float* logits = (float*)(ws + OFF_LOGITS);
  float* scores = (float*)(ws + OFF_SCORES);
  float* query  = (float*)(ws + OFF_QUERY);
  float* q2     = (float*)(ws + OFF_Q2);
  float* AH     = (float*)(ws + OFF_AH);
  float* A2     = (float*)(ws + OFF_A2);
  float* consts = (float*)(ws + OFF_CONSTS);
  unsigned char* bimg = (unsigned char*)(ws + OFF_BIMG);
  float* lstat  = (float*)(ws + OFF_LSTAT);
  float* MZ     = (float*)(ws + OFF_MZ);
  float* kattn  = (float*)(ws + OFF_KATTN);
  float* kb     = (float*)(ws + OFF_KB);
  float* upart  = (float*)(ws + OFF_UPART);
  float* tpart  = (float*)(ws + OFF_TPART);
  float* U      = (float*)(ws + OFF_U);
  float* T      = (float*)(ws + OFF_T);
  float* p3stat = (float*)(ws + OFF_P3STAT);
  float* MZ3    = (float*)(ws + OFF_MZ3);

  k_query <<<256, 256, 0, stream>>>(ctx, Wc, bc, query);
  k_q2    <<<256, 256, 0, stream>>>(query, ipw, ipb, q2);
  k_A     <<<8,   256, 0, stream>>>(q2, ipw, ipb, AH, consts);
  k_A2    <<<8,   256, 0, stream>>>(AH, Wk, bk, A2, consts);
  k_bimg  <<<66,  256, 0, stream>>>(Wk, Wv, A2, bimg);
  k_main  <<<3125,256, 0, stream>>>(emb, bimg, mask, consts, rk, rv, logits);
  k_lstats<<<64,  256, 0, stream>>>(logits, lstat);
  k_mz    <<<1,   64,  0, stream>>>(lstat, MZ);
  k_wsum  <<<512, 256, 0, stream>>>(emb, logits, rv, MZ, upart, tpart);
  k_ured  <<<8,   256, 0, stream>>>(upart, tpart, U, T);
  k_attn  <<<1,   256, 0, stream>>>(U, T, MZ, Wv, bv, ipw, ipb, opw, opb, Wo, bo, Wk, bk, kattn, kb);
  k_scores<<<512, 256, 0, stream>>>(emb, rk, mask, kattn, kb, scores, p3stat);
  k_mz3   <<<1,   256, 0, stream>>>(p3stat, MZ3);
  k_probs <<<512, 256, 0, stream>>>(scores, MZ3, out);
}

// Round 2
// 381.808 us; speedup vs baseline: 1.1581x; 1.1581x over previous
//
#include <hip/hip_runtime.h>

#define NN 200000
#define NEGV -1000000000.0f

typedef __attribute__((ext_vector_type(8))) short bf16x8;
typedef __attribute__((ext_vector_type(4))) float f32x4;

__device__ __forceinline__ float bf2f(unsigned short u){
  unsigned int x = ((unsigned int)u) << 16;
  return __builtin_bit_cast(float, x);
}
__device__ __forceinline__ unsigned short f2bf(float f){
  unsigned int x = __builtin_bit_cast(unsigned int, f);
  x += 0x7fffu + ((x >> 16) & 1u);
  return (unsigned short)(x >> 16);
}
__device__ __forceinline__ void gload16(const void* g, void* l){
  __builtin_amdgcn_global_load_lds((const __attribute__((address_space(1))) unsigned int*)g,
                                   (__attribute__((address_space(3))) unsigned int*)l, 16, 0, 0);
}

// ---------------- workspace layout (bytes) ----------------
static constexpr size_t OFF_RK     = 0;
static constexpr size_t OFF_RV     = 800256;
static constexpr size_t OFF_LOGITS = 1600512;   // [n][8] f32
static constexpr size_t OFF_SCORES = 8000512;
static constexpr size_t OFF_QUERY  = 8800768;
static constexpr size_t OFF_Q2     = 8801792;
static constexpr size_t OFF_A2     = 8802816;
static constexpr size_t OFF_CONSTS = 8811008;
static constexpr size_t OFF_BIMG   = 8811264;   // 8*528*64
static constexpr size_t OFF_LSTAT  = 9081600;   // 128*8*2 f32
static constexpr size_t OFF_MZ     = 9089792;
static constexpr size_t OFF_KATTN  = 9089856;
static constexpr size_t OFF_KB     = 9090880;
static constexpr size_t OFF_UPART  = 9090944;   // 512*2048 f32
static constexpr size_t OFF_TPART  = 13285248;  // 512*8 f32
static constexpr size_t OFF_U      = 13301632;
static constexpr size_t OFF_T      = 13309824;
static constexpr size_t OFF_P3STAT = 13309888;  // 512*2
static constexpr size_t OFF_MZ3    = 13313984;
static constexpr size_t OFF_EMBBF  = 13314048;  // N*256 bf16 = 102.4MB
static constexpr size_t WS_NEED_BF = OFF_EMBBF + (size_t)NN*512;

// ---------------- tiny prep chain ----------------
__global__ void k_query(const float* __restrict__ ctx, const float* __restrict__ Wc,
                        const float* __restrict__ bc, float* __restrict__ query){
  int e = blockIdx.x, t = threadIdx.x;
  float p = 0.f;
  #pragma unroll
  for (int r = 0; r < 3; r++){ int j = r*256 + t; p += ctx[j] * Wc[e*768 + j]; }
  #pragma unroll
  for (int m = 32; m; m >>= 1) p += __shfl_xor(p, m);
  __shared__ float red[4];
  if ((t & 63) == 0) red[t >> 6] = p;
  __syncthreads();
  if (t == 0) query[e] = red[0] + red[1] + red[2] + red[3] + bc[e];
}

__global__ void k_q2(const float* __restrict__ query, const float* __restrict__ ipw,
                     const float* __restrict__ ipb, float* __restrict__ q2){
  int d = blockIdx.x, t = threadIdx.x;
  float p = query[t] * ipw[d*256 + t];
  #pragma unroll
  for (int m = 32; m; m >>= 1) p += __shfl_xor(p, m);
  __shared__ float red[4];
  if ((t & 63) == 0) red[t >> 6] = p;
  __syncthreads();
  if (t == 0) q2[d] = red[0] + red[1] + red[2] + red[3] + ipb[d];
}

// fused k_A + k_A2
__global__ void k_AA(const float* __restrict__ q2, const float* __restrict__ ipw,
                     const float* __restrict__ ipb, const float* __restrict__ Wk,
                     const float* __restrict__ bk, float* __restrict__ A2,
                     float* __restrict__ consts){
  int h = blockIdx.x, t = threadIdx.x;
  __shared__ float qs[32];
  __shared__ float AHs[256];
  __shared__ float red[4];
  if (t < 32) qs[t] = q2[h*32 + t];
  __syncthreads();
  float a = 0.f;
  #pragma unroll
  for (int d = 0; d < 32; d++) a += qs[d] * ipw[(256 + h*32 + d)*256 + t];
  AHs[t] = a;
  if (t == 0){
    float ck = 0.f;
    for (int d = 0; d < 32; d++) ck += qs[d] * ipb[256 + h*32 + d];
    consts[8 + h] = ck;
  }
  __syncthreads();
  float a2 = 0.f;
  for (int e = 0; e < 256; e++) a2 += AHs[e] * Wk[e*256 + t];
  A2[h*256 + t] = a2;
  float cc = AHs[t] * bk[t];
  #pragma unroll
  for (int m = 32; m; m >>= 1) cc += __shfl_xor(cc, m);
  if ((t & 63) == 0) red[t >> 6] = cc;
  __syncthreads();
  if (t == 0) consts[h] = red[0] + red[1] + red[2] + red[3];
}

// Pre-swizzled bf16 B image (same layout as before)
__global__ void k_bimg(const float* __restrict__ Wk, const float* __restrict__ Wv,
                       const float* __restrict__ A2, unsigned char* __restrict__ bimg){
  int g = blockIdx.x*256 + threadIdx.x;
  if (g >= 8*528*4) return;
  int s = g / (528*4);
  int rem = g % (528*4);
  int col = rem >> 2, kg = rem & 3;
  int j0 = s*32 + kg*8;
  const float* src = nullptr;
  if (col < 256) src = Wk + col*256 + j0;
  else if (col < 512) src = Wv + (col-256)*256 + j0;
  else if (col < 520) src = A2 + (col-512)*256 + j0;
  unsigned short u[8];
  #pragma unroll
  for (int i = 0; i < 8; i++) u[i] = src ? f2bf(src[i]) : (unsigned short)0;
  uint4 o;
  o.x = (unsigned int)u[0] | ((unsigned int)u[1] << 16);
  o.y = (unsigned int)u[2] | ((unsigned int)u[3] << 16);
  o.z = (unsigned int)u[4] | ((unsigned int)u[5] << 16);
  o.w = (unsigned int)u[6] | ((unsigned int)u[7] << 16);
  unsigned int addr = (unsigned int)((col*64 + kg*16) ^ ((col & 7) << 4));
  *(uint4*)(bimg + (size_t)s*33792 + addr) = o;
}

// ---------------- main fused GEMM ----------------
// 4 waves; wave w owns col-frags [w*8 .. w*8+7] + shared frag 32 (logits);
// 64 nodes/block, 4 node-strips of 16; double-buffered per-step tiles.
__launch_bounds__(256, 2)
__global__ void k_main(const float* __restrict__ emb, const unsigned char* __restrict__ bimg,
                       const int* __restrict__ mask, const float* __restrict__ consts,
                       float* __restrict__ rk_g, float* __restrict__ rv_g,
                       float* __restrict__ logits, unsigned char* __restrict__ ebf){
  __shared__ __align__(16) unsigned char smA[2][4096];
  __shared__ __align__(16) unsigned char smB[2][33792];
  __shared__ float sc_norm[4][64];
  __shared__ float rkbuf[64];
  const int tid = threadIdx.x;
  const int lane = tid & 63, wave = tid >> 6;
  const int c = lane & 15, kg = lane >> 4;
  const int nb0 = blockIdx.x * 64;

  auto stage = [&](int s, int buf){
    // B: 33 chunks of 1KB via global_load_lds (bimg pre-swizzled)
    const unsigned char* bsrc = bimg + (size_t)s*33792;
    #pragma unroll
    for (int it = 0; it < 9; it++){
      int chunk = it*4 + wave;
      if (chunk < 33)
        gload16(bsrc + chunk*1024 + lane*16, &smB[buf][chunk*1024]);
    }
    // A: 256 granules, reg-staged fp32->bf16, swizzled ds_write; also dump bf16 emb copy
    int nl = tid >> 2, akg = tid & 3;
    const float* ap = emb + (size_t)(nb0 + nl)*256 + s*32 + akg*8;
    float4 f0 = *(const float4*)ap;
    float4 f1 = *(const float4*)(ap + 4);
    uint4 o;
    o.x = (unsigned int)f2bf(f0.x) | ((unsigned int)f2bf(f0.y) << 16);
    o.y = (unsigned int)f2bf(f0.z) | ((unsigned int)f2bf(f0.w) << 16);
    o.z = (unsigned int)f2bf(f1.x) | ((unsigned int)f2bf(f1.y) << 16);
    o.w = (unsigned int)f2bf(f1.z) | ((unsigned int)f2bf(f1.w) << 16);
    *(uint4*)&smA[buf][nl*64 + ((akg ^ ((nl >> 1) & 3)) << 4)] = o;
    if (ebf) *(uint4*)(ebf + (size_t)(nb0 + nl)*512 + s*64 + akg*16) = o;
  };

  f32x4 acc[4][9];
  #pragma unroll
  for (int st = 0; st < 4; st++)
    #pragma unroll
    for (int f = 0; f < 9; f++) acc[st][f] = (f32x4){0.f,0.f,0.f,0.f};

  stage(0, 0);
  for (int s = 0; s < 8; s++){
    int cur = s & 1;
    __syncthreads();                 // stage(s) done for all waves; MFMA(s-1) done -> safe to stage s+1
    if (s < 7) stage(s + 1, cur ^ 1);
    bf16x8 af[4];
    #pragma unroll
    for (int st = 0; st < 4; st++)
      af[st] = *(const bf16x8*)&smA[cur][st*1024 + c*64 + ((kg ^ ((c >> 1) & 3)) << 4)];
    #pragma unroll
    for (int f = 0; f < 9; f++){
      int cf = (f < 8) ? (wave*8 + f) : 32;
      bf16x8 bf = *(const bf16x8*)&smB[cur][(((cf*16 + c)*64 + kg*16)) ^ ((c & 7) << 4)];
      #pragma unroll
      for (int st = 0; st < 4; st++)
        acc[st][f] = __builtin_amdgcn_mfma_f32_16x16x32_bf16(af[st], bf, acc[st][f], 0, 0, 0);
    }
  }

  // Epilogue: norms (frags 0..7 of each wave; waves 0,1 = K-cols, 2,3 = V-cols)
  #pragma unroll
  for (int st = 0; st < 4; st++){
    #pragma unroll
    for (int i = 0; i < 4; i++){
      float p = 0.f;
      #pragma unroll
      for (int f = 0; f < 8; f++) p += acc[st][f][i]*acc[st][f][i];
      #pragma unroll
      for (int m = 1; m < 16; m <<= 1) p += __shfl_xor(p, m);
      if (c == 0) sc_norm[wave][st*16 + kg*4 + i] = p;
    }
  }
  __syncthreads();
  if (tid < 64){
    float pk = sc_norm[0][tid] + sc_norm[1][tid];
    float pv = sc_norm[2][tid] + sc_norm[3][tid];
    float rk = fmaxf(sqrtf(pk), 1e-12f);
    float rv = fmaxf(sqrtf(pv), 1e-12f);
    rk_g[nb0 + tid] = rk; rv_g[nb0 + tid] = rv;
    rkbuf[tid] = rk;
  }
  __syncthreads();
  if (wave == 3 && c < 8){
    const float rs32 = 0.17677669529663688f;
    float cb = consts[c], ck = consts[8 + c];
    #pragma unroll
    for (int st = 0; st < 4; st++){
      #pragma unroll
      for (int i = 0; i < 4; i++){
        int nl = st*16 + kg*4 + i;
        int n = nb0 + nl;
        float lg = (mask[n] == 0) ? ((acc[st][8][i] + cb)*rs32/rkbuf[nl] + ck*rs32) : NEGV;
        logits[(size_t)n*8 + c] = lg;
      }
    }
  }
}

// ---------------- logits softmax stats ([n][8] layout) ----------------
__global__ void k_lstats(const float* __restrict__ logits, float* __restrict__ lstat){
  int tid = threadIdx.x;
  float m[8], z[8];
  #pragma unroll
  for (int h = 0; h < 8; h++){ m[h] = -3.0e38f; z[h] = 0.f; }
  for (int n = blockIdx.x*256 + tid; n < NN; n += 128*256){
    float4 a = *(const float4*)(logits + (size_t)n*8);
    float4 b = *(const float4*)(logits + (size_t)n*8 + 4);
    float l[8] = {a.x,a.y,a.z,a.w,b.x,b.y,b.z,b.w};
    #pragma unroll
    for (int h = 0; h < 8; h++){
      float M = fmaxf(m[h], l[h]);
      z[h] = z[h]*expf(m[h]-M) + expf(l[h]-M);
      m[h] = M;
    }
  }
  #pragma unroll
  for (int s = 1; s < 64; s <<= 1){
    #pragma unroll
    for (int h = 0; h < 8; h++){
      float m2 = __shfl_xor(m[h], s), z2 = __shfl_xor(z[h], s);
      float M = fmaxf(m[h], m2);
      z[h] = z[h]*expf(m[h]-M) + z2*expf(m2-M);
      m[h] = M;
    }
  }
  __shared__ float sm[4][8], sz[4][8];
  int wave = tid >> 6, lane = tid & 63;
  if (lane == 0){
    #pragma unroll
    for (int h = 0; h < 8; h++){ sm[wave][h] = m[h]; sz[wave][h] = z[h]; }
  }
  __syncthreads();
  if (tid < 8){
    float M = sm[0][tid], Z = sz[0][tid];
    #pragma unroll
    for (int w = 1; w < 4; w++){
      float M2 = fmaxf(M, sm[w][tid]);
      Z = Z*expf(M-M2) + sz[w][tid]*expf(sm[w][tid]-M2);
      M = M2;
    }
    lstat[(blockIdx.x*8 + tid)*2] = M;
    lstat[(blockIdx.x*8 + tid)*2 + 1] = Z;
  }
}

__global__ void k_mz(const float* __restrict__ lstat, float* __restrict__ MZ){
  int t = threadIdx.x;
  int h = t >> 3, seg = t & 7;
  float m = -3.0e38f, z = 0.f;
  for (int k = 0; k < 16; k++){
    int b = seg*16 + k;
    float m2 = lstat[(b*8 + h)*2], z2 = lstat[(b*8 + h)*2 + 1];
    float M = fmaxf(m, m2); z = z*expf(m-M) + z2*expf(m2-M); m = M;
  }
  #pragma unroll
  for (int s = 1; s < 8; s <<= 1){
    float m2 = __shfl_xor(m, s), z2 = __shfl_xor(z, s);
    float M = fmaxf(m, m2); z = z*expf(m-M) + z2*expf(m2-M); m = M;
  }
  if (seg == 0){ MZ[h] = m; MZ[8+h] = z; }
}

// ---------------- weighted emb reduction ----------------
template<int BF>
__launch_bounds__(256)
__global__ void k_wsum(const void* __restrict__ embsrc, const float* __restrict__ logits,
                       const float* __restrict__ rv_g, const float* __restrict__ MZ,
                       float* __restrict__ upart, float* __restrict__ tpart){
  int tid = threadIdx.x, lane = tid & 63, wave = tid >> 6;
  int hl = lane & 31, h2 = lane >> 5;
  int gw = blockIdx.x*4 + wave;
  float Mh = MZ[hl & 7];
  float ua[8][8];
  #pragma unroll
  for (int h = 0; h < 8; h++)
    #pragma unroll
    for (int j = 0; j < 8; j++) ua[h][j] = 0.f;
  float tacc = 0.f;
  for (int p = gw; p < NN/2; p += 2048){
    int n = 2*p + h2;
    float e[8];
    if (BF){
      uint4 g = *(const uint4*)((const unsigned char*)embsrc + (size_t)n*512 + hl*16);
      e[0]=bf2f((unsigned short)(g.x&0xffff)); e[1]=bf2f((unsigned short)(g.x>>16));
      e[2]=bf2f((unsigned short)(g.y&0xffff)); e[3]=bf2f((unsigned short)(g.y>>16));
      e[4]=bf2f((unsigned short)(g.z&0xffff)); e[5]=bf2f((unsigned short)(g.z>>16));
      e[6]=bf2f((unsigned short)(g.w&0xffff)); e[7]=bf2f((unsigned short)(g.w>>16));
    } else {
      const float* ep = (const float*)embsrc + (size_t)n*256 + hl*8;
      float4 a = *(const float4*)ep, b = *(const float4*)(ep + 4);
      e[0]=a.x; e[1]=a.y; e[2]=a.z; e[3]=a.w; e[4]=b.x; e[5]=b.y; e[6]=b.z; e[7]=b.w;
    }
    float coef = 0.f;
    if (hl < 8) coef = expf(logits[(size_t)n*8 + hl] - Mh) / rv_g[n];
    tacc += coef;
    #pragma unroll
    for (int h = 0; h < 8; h++){
      float ch = __shfl(coef, h, 32);
      #pragma unroll
      for (int j = 0; j < 8; j++) ua[h][j] += ch * e[j];
    }
  }
  #pragma unroll
  for (int h = 0; h < 8; h++)
    #pragma unroll
    for (int j = 0; j < 8; j++) ua[h][j] += __shfl_xor(ua[h][j], 32);
  tacc += __shfl_xor(tacc, 32);
  __shared__ float ub[4][8][256];
  __shared__ float tb[4][8];
  if (h2 == 0){
    #pragma unroll
    for (int h = 0; h < 8; h++)
      #pragma unroll
      for (int j = 0; j < 8; j++) ub[wave][h][hl*8 + j] = ua[h][j];
    if (hl < 8) tb[wave][hl] = tacc;
  }
  __syncthreads();
  #pragma unroll
  for (int rep = 0; rep < 8; rep++){
    int idx = rep*256 + tid;
    int h = idx >> 8, j = idx & 255;
    upart[(size_t)blockIdx.x*2048 + h*256 + j] = ub[0][h][j]+ub[1][h][j]+ub[2][h][j]+ub[3][h][j];
  }
  if (tid < 8) tpart[blockIdx.x*8 + tid] = tb[0][tid]+tb[1][tid]+tb[2][tid]+tb[3][tid];
}

__global__ void k_ured(const float* __restrict__ upart, const float* __restrict__ tpart,
                       float* __restrict__ U, float* __restrict__ T){
  int h = blockIdx.x, j = threadIdx.x;
  float s = 0.f;
  for (int b = 0; b < 512; b++) s += upart[(size_t)b*2048 + h*256 + j];
  U[h*256 + j] = s;
  float tp = 0.f;
  if (j < 64){
    for (int i = 0; i < 8; i++) tp += tpart[(j*8 + i)*8 + h];
  }
  #pragma unroll
  for (int m = 1; m < 64; m <<= 1) tp += __shfl_xor(tp, m);
  if (j == 0) T[h] = tp;
}

// ---------------- tiny attention/projection chain ----------------
__global__ void k_attn(const float* __restrict__ U, const float* __restrict__ T,
                       const float* __restrict__ MZ,
                       const float* __restrict__ Wv, const float* __restrict__ bv,
                       const float* __restrict__ ipw, const float* __restrict__ ipb,
                       const float* __restrict__ opw, const float* __restrict__ opb,
                       const float* __restrict__ Wo, const float* __restrict__ bo,
                       const float* __restrict__ Wk, const float* __restrict__ bk,
                       float* __restrict__ kattn, float* __restrict__ kbout){
  int t = threadIdx.x;
  __shared__ float u[8][256], sh[8][256];
  __shared__ float a1[256], o1[256], af[256];
  __shared__ float red[4];
  #pragma unroll
  for (int h = 0; h < 8; h++) u[h][t] = U[h*256 + t];
  __syncthreads();
  {
    float accs[8];
    #pragma unroll
    for (int h = 0; h < 8; h++) accs[h] = 0.f;
    for (int j = 0; j < 256; j++){
      float wv = Wv[t*256 + j];
      #pragma unroll
      for (int h = 0; h < 8; h++) accs[h] += wv * u[h][j];
    }
    #pragma unroll
    for (int h = 0; h < 8; h++) sh[h][t] = (accs[h] + bv[t]*T[h]) / MZ[8+h];
  }
  __syncthreads();
  {
    int h = t >> 5;
    float a = 0.f;
    for (int j = 0; j < 256; j++) a += ipw[(512 + t)*256 + j] * sh[h][j];
    a1[t] = a + ipb[512 + t];
  }
  __syncthreads();
  { float a = 0.f; for (int j = 0; j < 256; j++) a += opw[t*256 + j]*a1[j]; o1[t] = a + opb[t]; }
  __syncthreads();
  float o2v;
  { float a = 0.f; for (int j = 0; j < 256; j++) a += Wo[t*256 + j]*o1[j]; o2v = a + bo[t]; }
  {
    float sq = o2v*o2v;
    #pragma unroll
    for (int m = 1; m < 64; m <<= 1) sq += __shfl_xor(sq, m);
    if ((t & 63) == 0) red[t >> 6] = sq;
    __syncthreads();
    float nrm = fmaxf(sqrtf(red[0]+red[1]+red[2]+red[3]), 1e-12f);
    af[t] = o2v / nrm;
  }
  __syncthreads();
  { float a = 0.f; for (int e = 0; e < 256; e++) a += af[e]*Wk[e*256 + t]; kattn[t] = a; }
  {
    float cc = af[t]*bk[t];
    #pragma unroll
    for (int m = 1; m < 64; m <<= 1) cc += __shfl_xor(cc, m);
    __syncthreads();
    if ((t & 63) == 0) red[t >> 6] = cc;
    __syncthreads();
    if (t == 0) kbout[0] = red[0]+red[1]+red[2]+red[3];
  }
}

// ---------------- scores + online softmax stats ----------------
template<int BF>
__launch_bounds__(256)
__global__ void k_scores(const void* __restrict__ embsrc, const float* __restrict__ rk_g,
                         const int* __restrict__ mask, const float* __restrict__ kattn,
                         const float* __restrict__ kbp, float* __restrict__ scores,
                         float* __restrict__ p3stat){
  int tid = threadIdx.x, lane = tid & 63, wave = tid >> 6;
  int hl = lane & 31, h2 = lane >> 5;
  __shared__ float ka[256];
  ka[tid] = kattn[tid];
  __syncthreads();
  float kb = kbp[0];
  float kv[8];
  #pragma unroll
  for (int j = 0; j < 8; j++) kv[j] = ka[hl*8 + j];
  int gw = blockIdx.x*4 + wave;
  float m = -3.0e38f, z = 0.f;
  for (int p = gw; p < NN/2; p += 2048){
    int n = 2*p + h2;
    float d;
    if (BF){
      uint4 g = *(const uint4*)((const unsigned char*)embsrc + (size_t)n*512 + hl*16);
      d  = bf2f((unsigned short)(g.x&0xffff))*kv[0] + bf2f((unsigned short)(g.x>>16))*kv[1];
      d += bf2f((unsigned short)(g.y&0xffff))*kv[2] + bf2f((unsigned short)(g.y>>16))*kv[3];
      d += bf2f((unsigned short)(g.z&0xffff))*kv[4] + bf2f((unsigned short)(g.z>>16))*kv[5];
      d += bf2f((unsigned short)(g.w&0xffff))*kv[6] + bf2f((unsigned short)(g.w>>16))*kv[7];
    } else {
      const float* ep = (const float*)embsrc + (size_t)n*256 + hl*8;
      float4 a = *(const float4*)ep, b = *(const float4*)(ep + 4);
      d = a.x*kv[0]+a.y*kv[1]+a.z*kv[2]+a.w*kv[3]+b.x*kv[4]+b.y*kv[5]+b.z*kv[6]+b.w*kv[7];
    }
    #pragma unroll
    for (int s = 1; s < 32; s <<= 1) d += __shfl_xor(d, s);
    if (hl == 0){
      float sc = (mask[n] == 0) ? ((d + kb) / rk_g[n]) : NEGV;
      scores[n] = sc;
      float M = fmaxf(m, sc);
      z = z*expf(m - M) + expf(sc - M);
      m = M;
    }
  }
  float m2 = __shfl_xor(m, 32), z2 = __shfl_xor(z, 32);
  float M = fmaxf(m, m2); z = z*expf(m-M) + z2*expf(m2-M); m = M;
  __shared__ float rm[4], rz[4];
  if (lane == 0){ rm[wave] = m; rz[wave] = z; }
  __syncthreads();
  if (tid == 0){
    float Mx = rm[0], Z = rz[0];
    for (int w = 1; w < 4; w++){
      float M2 = fmaxf(Mx, rm[w]);
      Z = Z*expf(Mx - M2) + rz[w]*expf(rm[w] - M2);
      Mx = M2;
    }
    p3stat[blockIdx.x*2] = Mx; p3stat[blockIdx.x*2+1] = Z;
  }
}

__global__ void k_mz3(const float* __restrict__ p3stat, float* __restrict__ MZ3){
  int t = threadIdx.x;
  float m = p3stat[t*2], z = p3stat[t*2+1];
  {
    float m2 = p3stat[(t+256)*2], z2 = p3stat[(t+256)*2+1];
    float M = fmaxf(m, m2); z = z*expf(m-M) + z2*expf(m2-M); m = M;
  }
  #pragma unroll
  for (int mm = 1; mm < 64; mm <<= 1){
    float ms = __shfl_xor(m, mm), zs = __shfl_xor(z, mm);
    float Mx = fmaxf(m, ms); z = z*expf(m-Mx) + zs*expf(ms-Mx); m = Mx;
  }
  __shared__ float rm[4], rz[4];
  if ((t&63)==0){ rm[t>>6]=m; rz[t>>6]=z; }
  __syncthreads();
  if (t==0){
    float M=rm[0], Z=rz[0];
    for (int w=1; w<4; w++){ float Mx=fmaxf(M,rm[w]); Z=Z*expf(M-Mx)+rz[w]*expf(rm[w]-Mx); M=Mx; }
    MZ3[0]=M; MZ3[1]=Z;
  }
}

__global__ void k_probs(const float* __restrict__ scores, const float* __restrict__ MZ3,
                        float* __restrict__ out){
  float M = MZ3[0], iZ = 1.0f / MZ3[1];
  for (int n = blockIdx.x*256 + threadIdx.x; n < NN; n += 512*256)
    out[n] = expf(scores[n] - M) * iZ;
}

// ---------------- launcher ----------------
extern "C" void kernel_launch(void* const* d_in, const int* in_sizes, int n_in,
                              void* d_out, int out_size, void* d_ws, size_t ws_size,
                              hipStream_t stream){
  (void)in_sizes; (void)n_in; (void)out_size;
  const float* ctx = (const float*)d_in[0];
  const float* emb = (const float*)d_in[1];
  const int*   mask= (const int*)d_in[2];
  const float* Wc  = (const float*)d_in[3];
  const float* bc  = (const float*)d_in[4];
  const float* Wk  = (const float*)d_in[5];
  const float* bk  = (const float*)d_in[6];
  const float* Wv  = (const float*)d_in[7];
  const float* bv  = (const float*)d_in[8];
  const float* ipw = (const float*)d_in[9];
  const float* ipb = (const float*)d_in[10];
  const float* opw = (const float*)d_in[11];
  const float* opb = (const float*)d_in[12];
  const float* Wo  = (const float*)d_in[13];
  const float* bo  = (const float*)d_in[14];
  float* out = (float*)d_out;
  char* ws = (char*)d_ws;

  float* rk     = (float*)(ws + OFF_RK);
  float* rv     = (float*)(ws + OFF_RV);
  float* logits = (float*)(ws + OFF_LOGITS);
  float* scores = (float*)(ws + OFF_SCORES);
  float* query  = (float*)(ws + OFF_QUERY);
  float* q2     = (float*)(ws + OFF_Q2);
  float* A2     = (float*)(ws + OFF_A2);
  float* consts = (float*)(ws + OFF_CONSTS);
  unsigned char* bimg = (unsigned char*)(ws + OFF_BIMG);
  float* lstat  = (float*)(ws + OFF_LSTAT);
  float* MZ     = (float*)(ws + OFF_MZ);
  float* kattn  = (float*)(ws + OFF_KATTN);
  float* kb     = (float*)(ws + OFF_KB);
  float* upart  = (float*)(ws + OFF_UPART);
  float* tpart  = (float*)(ws + OFF_TPART);
  float* U      = (float*)(ws + OFF_U);
  float* T      = (float*)(ws + OFF_T);
  float* p3stat = (float*)(ws + OFF_P3STAT);
  float* MZ3    = (float*)(ws + OFF_MZ3);

  const bool bf = ws_size >= WS_NEED_BF;
  unsigned char* ebf = bf ? (unsigned char*)(ws + OFF_EMBBF) : nullptr;

  k_query <<<256, 256, 0, stream>>>(ctx, Wc, bc, query);
  k_q2    <<<256, 256, 0, stream>>>(query, ipw, ipb, q2);
  k_AA    <<<8,   256, 0, stream>>>(q2, ipw, ipb, Wk, bk, A2, consts);
  k_bimg  <<<66,  256, 0, stream>>>(Wk, Wv, A2, bimg);
  k_main  <<<3125,256, 0, stream>>>(emb, bimg, mask, consts, rk, rv, logits, ebf);
  k_lstats<<<128, 256, 0, stream>>>(logits, lstat);
  k_mz    <<<1,   64,  0, stream>>>(lstat, MZ);
  if (bf) k_wsum<1><<<512, 256, 0, stream>>>(ebf, logits, rv, MZ, upart, tpart);
  else    k_wsum<0><<<512, 256, 0, stream>>>(emb, logits, rv, MZ, upart, tpart);
  k_ured  <<<8,   256, 0, stream>>>(upart, tpart, U, T);
  k_attn  <<<1,   256, 0, stream>>>(U, T, MZ, Wv, bv, ipw, ipb, opw, opb, Wo, bo, Wk, bk, kattn, kb);
  if (bf) k_scores<1><<<512, 256, 0, stream>>>(ebf, rk, mask, kattn, kb, scores, p3stat);
  else    k_scores<0><<<512, 256, 0, stream>>>(emb, rk, mask, kattn, kb, scores, p3stat);
  k_mz3   <<<1,   256, 0, stream>>>(p3stat, MZ3);
  k_probs <<<512, 256, 0, stream>>>(scores, MZ3, out);
}